// Round 1
// baseline (288.633 us; speedup 1.0000x reference)
//
#include <hip/hip_runtime.h>

typedef unsigned short u16;
typedef unsigned int u32;
typedef __attribute__((ext_vector_type(8))) short bf16x8;
typedef __attribute__((ext_vector_type(4))) float f32x4;
typedef __attribute__((ext_vector_type(4))) u16 u16x4;

#define B_ 64
#define R_ 2
#define T_ 32
#define N_ 128
#define C_ 64

__device__ __forceinline__ u16 f2bf(float f) {
  u32 u = __builtin_bit_cast(u32, f);
  u = (u + 0x7FFFu + ((u >> 16) & 1u)) >> 16;
  return (u16)u;
}
__device__ __forceinline__ float bf2f(u16 h) {
  u32 u = ((u32)h) << 16;
  return __builtin_bit_cast(float, u);
}

#define MFMA __builtin_amdgcn_mfma_f32_16x16x32_bf16

// ---------------------------------------------------------------------------
// K1: per (b,t): A copy -> d_out, normalized laplacian, gcn 1x1 conv (MFMA),
// bmm with A_norm (MFMA), write x_comb as bf16 (b,t,n,c) to ws.
// ---------------------------------------------------------------------------
__global__ __launch_bounds__(256, 2) void k_gcn(
    const float* __restrict__ x, const float* __restrict__ A,
    const float* __restrict__ wg, const float* __restrict__ bg,
    float* __restrict__ outA, u16* __restrict__ wsX) {
  // LDS: 18432 + 9216 + 34816 + 17408 + 512 + 256 = 80640 B -> 2 blocks/CU
  __shared__ __align__(16) u16 XT[N_][72];    // X^T [n][c] (B-operand, k=c contig)
  __shared__ __align__(16) u16 WL[C_][72];    // W_r [o][c] (A-operand)
  __shared__ __align__(16) u16 AT[N_][136];   // A^T  [m][n] (B-operand, k=n contig)
  __shared__ __align__(16) u16 TMP[C_][136];  // tmp [c][n] (A-operand)
  __shared__ float dinv[N_];
  __shared__ float bgc[C_];

  const int tid = threadIdx.x;
  const int bi = blockIdx.x;
  const int b = bi >> 5, t = bi & 31;
  const int lane = tid & 63, wv = tid >> 6;
  const int wr = wv >> 1, wc = wv & 1;   // wave tile: rows 32*wr, cols 64*wc
  const int lr = lane & 15, lg = lane >> 4;

  // ---- stage X^T (bf16). lanes vary c -> conflict-free LDS writes.
  {
    const int c = tid & 63;
    const int ub = tid >> 6;
    const float* xp = x + ((size_t)(b * C_ + c) * T_ + t) * N_;
#pragma unroll
    for (int it = 0; it < 8; ++it) {
      int u = it * 4 + ub;  // float4 chunk 0..31
      float4 v = *(const float4*)(xp + 4 * u);
      XT[4 * u + 0][c] = f2bf(v.x);
      XT[4 * u + 1][c] = f2bf(v.y);
      XT[4 * u + 2][c] = f2bf(v.z);
      XT[4 * u + 3][c] = f2bf(v.w);
    }
  }

  f32x4 acc2[2][4] = {};
  float* rs = (float*)&TMP[0][0];  // rowsum scratch aliases TMP (dead by then)

  for (int r = 0; r < R_; ++r) {
    __syncthreads();  // XT ready (r=0) / previous matmul2 readers done (r=1)

    // ---- stage W_r + b_gcn[r]
    for (int i = tid; i < C_ * C_; i += 256)
      WL[i >> 6][i & 63] = f2bf(wg[(r * C_ + (i >> 6)) * C_ + (i & 63)]);
    if (tid < C_) bgc[tid] = bg[r * C_ + tid];

    // ---- stage A -> AT (transposed bf16), copy A -> outA, per-row sums
    {
      const int n = tid & 127;
      const int half = tid >> 7;
      const size_t sl = ((size_t)((b * R_ + r) * T_ + t) * N_ + n) * N_;
      const float* Ap = A + sl;
      float* Op = outA + sl;
      float part = 0.f;
#pragma unroll
      for (int it = 0; it < 16; ++it) {
        int m4 = it * 2 + half;  // 16B chunk of row n
        float4 v = *(const float4*)(Ap + 4 * m4);
        *(float4*)(Op + 4 * m4) = v;
        part += (v.x + v.y) + (v.z + v.w);
        AT[4 * m4 + 0][n] = f2bf(v.x);  // lane-contiguous in n: conflict-free
        AT[4 * m4 + 1][n] = f2bf(v.y);
        AT[4 * m4 + 2][n] = f2bf(v.z);
        AT[4 * m4 + 3][n] = f2bf(v.w);
      }
      rs[tid] = part;
    }
    __syncthreads();  // rs, raw AT, WL ready
    if (tid < N_) dinv[tid] = rsqrtf(rs[tid] + rs[tid + 128] + 1.0f);
    __syncthreads();  // dinv ready; rs dead from here (TMP reusable)

    // ---- scale AT in place: AT[m][n] = (A[n][m] + I) * dinv[n]*dinv[m]
    for (int i = tid; i < N_ * N_; i += 256) {
      int m = i >> 7, n = i & 127;
      float v = bf2f(AT[m][n]);
      if (m == n) v += 1.0f;
      v *= dinv[m] * dinv[n];
      AT[m][n] = f2bf(v);
    }

    // ---- matmul1: TMP[o][n] = sum_c WL[o][c]*X[c][n] + bgc[o]
    {
      f32x4 acc1[2][4] = {};
#pragma unroll
      for (int kk = 0; kk < 2; ++kk) {
        const int k0 = kk * 32 + lg * 8;
        bf16x8 af[2], bfr[4];
#pragma unroll
        for (int mr = 0; mr < 2; ++mr)
          af[mr] = *(const bf16x8*)&WL[32 * wr + 16 * mr + lr][k0];
#pragma unroll
        for (int nc = 0; nc < 4; ++nc)
          bfr[nc] = *(const bf16x8*)&XT[64 * wc + 16 * nc + lr][k0];
#pragma unroll
        for (int mr = 0; mr < 2; ++mr)
#pragma unroll
          for (int nc = 0; nc < 4; ++nc)
            acc1[mr][nc] = MFMA(af[mr], bfr[nc], acc1[mr][nc], 0, 0, 0);
      }
#pragma unroll
      for (int mr = 0; mr < 2; ++mr)
#pragma unroll
        for (int nc = 0; nc < 4; ++nc) {
          const int o = 32 * wr + 16 * mr + 4 * lg;
          const int n = 64 * wc + 16 * nc + lr;
#pragma unroll
          for (int i = 0; i < 4; ++i)
            TMP[o + i][n] = f2bf(acc1[mr][nc][i] + bgc[o + i]);
        }
    }
    __syncthreads();  // TMP + scaled AT ready

    // ---- matmul2: acc2[c][m] += sum_n TMP[c][n] * AT[m][n]
#pragma unroll
    for (int kk = 0; kk < 4; ++kk) {
      const int k0 = kk * 32 + lg * 8;
      bf16x8 af[2], bfr[4];
#pragma unroll
      for (int mr = 0; mr < 2; ++mr)
        af[mr] = *(const bf16x8*)&TMP[32 * wr + 16 * mr + lr][k0];
#pragma unroll
      for (int nc = 0; nc < 4; ++nc)
        bfr[nc] = *(const bf16x8*)&AT[64 * wc + 16 * nc + lr][k0];
#pragma unroll
      for (int mr = 0; mr < 2; ++mr)
#pragma unroll
        for (int nc = 0; nc < 4; ++nc)
          acc2[mr][nc] = MFMA(af[mr], bfr[nc], acc2[mr][nc], 0, 0, 0);
    }
  }

  // ---- epilogue: ws[b][t][m][c] = bf16(x_comb)
  {
    u16* wp = wsX + ((size_t)(b * T_ + t) * N_) * C_;
#pragma unroll
    for (int mr = 0; mr < 2; ++mr)
#pragma unroll
      for (int nc = 0; nc < 4; ++nc) {
        const int m = 64 * wc + 16 * nc + lr;
        const int cb = 32 * wr + 16 * mr + 4 * lg;
        u16x4 pk;
#pragma unroll
        for (int i = 0; i < 4; ++i) pk[i] = f2bf(acc2[mr][nc][i]);
        *(u16x4*)(wp + (size_t)m * C_ + cb) = pk;
      }
  }
}

// ---------------------------------------------------------------------------
// K2: per (b,t): h = prelu(x_comb); out = prelu(conv3_T(h) + b_tcn + x)
// conv as 64x192 @ 192x128 MFMA.
// ---------------------------------------------------------------------------
__global__ __launch_bounds__(256, 2) void k_tcn(
    const u16* __restrict__ wsX, const float* __restrict__ x,
    const float* __restrict__ wt, const float* __restrict__ bt,
    const float* __restrict__ a_tcn, const float* __restrict__ a_out,
    float* __restrict__ out) {
  __shared__ __align__(16) u16 HT[N_][200];  // H^T [n][k=dt*64+ci]
  __shared__ __align__(16) u16 W2[C_][200];  // W' [co][k]
  const int tid = threadIdx.x;
  const int bi = blockIdx.x;
  const int b = bi >> 5, t = bi & 31;
  const int lane = tid & 63, wv = tid >> 6;
  const int wr = wv >> 1, wc = wv & 1;
  const int lr = lane & 15, lg = lane >> 4;
  const float at = a_tcn[0], ao = a_out[0];

  for (int k = tid; k < C_ * C_ * 3; k += 256) {
    int co = k / 192;
    int rem = k - co * 192;
    int ci = rem / 3;
    int dt = rem - 3 * ci;
    W2[co][dt * 64 + ci] = f2bf(wt[k]);
  }
#pragma unroll
  for (int dt = 0; dt < 3; ++dt) {
    const int t2 = t + dt - 1;
    const bool ok = (t2 >= 0) && (t2 < T_);
    const u16* p = wsX + ((size_t)(b * T_ + (ok ? t2 : 0)) * N_) * C_;
#pragma unroll
    for (int it = 0; it < 8; ++it) {
      int idx = it * 256 + tid;
      int n = idx >> 4, c4 = (idx & 15) * 4;
      u16x4 v = {0, 0, 0, 0};
      if (ok) v = *(const u16x4*)(p + n * C_ + c4);
      u16x4 o;
#pragma unroll
      for (int j = 0; j < 4; ++j) {
        float f = bf2f(v[j]);
        f = (f < 0.f) ? at * f : f;
        o[j] = f2bf(f);
      }
      *(u16x4*)&HT[n][dt * 64 + c4] = o;
    }
  }
  __syncthreads();

  f32x4 acc[2][4] = {};
#pragma unroll
  for (int kk = 0; kk < 6; ++kk) {
    const int k0 = kk * 32 + lg * 8;
    bf16x8 af[2], bfr[4];
#pragma unroll
    for (int mr = 0; mr < 2; ++mr)
      af[mr] = *(const bf16x8*)&W2[32 * wr + 16 * mr + lr][k0];
#pragma unroll
    for (int nc = 0; nc < 4; ++nc)
      bfr[nc] = *(const bf16x8*)&HT[64 * wc + 16 * nc + lr][k0];
#pragma unroll
    for (int mr = 0; mr < 2; ++mr)
#pragma unroll
      for (int nc = 0; nc < 4; ++nc)
        acc[mr][nc] = MFMA(af[mr], bfr[nc], acc[mr][nc], 0, 0, 0);
  }

#pragma unroll
  for (int mr = 0; mr < 2; ++mr)
#pragma unroll
    for (int nc = 0; nc < 4; ++nc) {
      const int n = 64 * wc + 16 * nc + lr;
#pragma unroll
      for (int i = 0; i < 4; ++i) {
        const int co = 32 * wr + 16 * mr + 4 * lg + i;
        const size_t gi = ((size_t)(b * C_ + co) * T_ + t) * N_ + n;
        float v = acc[mr][nc][i] + bt[co] + x[gi];
        v = (v < 0.f) ? ao * v : v;
        out[gi] = v;
      }
    }
}

extern "C" void kernel_launch(void* const* d_in, const int* in_sizes, int n_in,
                              void* d_out, int out_size, void* d_ws, size_t ws_size,
                              hipStream_t stream) {
  const float* x = (const float*)d_in[0];
  const float* A = (const float*)d_in[1];
  const float* wg = (const float*)d_in[2];
  const float* bg = (const float*)d_in[3];
  const float* wt = (const float*)d_in[4];
  const float* bt = (const float*)d_in[5];
  const float* atc = (const float*)d_in[6];
  const float* aoc = (const float*)d_in[7];
  float* out = (float*)d_out;
  float* outA = out + (size_t)B_ * C_ * T_ * N_;  // second tuple element: A
  u16* wsX = (u16*)d_ws;  // bf16 x_comb, (B,T,N,C) = 33.5 MB

  k_gcn<<<B_ * T_, 256, 0, stream>>>(x, A, wg, bg, outA, wsX);
  k_tcn<<<B_ * T_, 256, 0, stream>>>(wsX, x, wt, bt, atc, aoc, out);
}

// Round 2
// 276.419 us; speedup vs baseline: 1.0442x; 1.0442x over previous
//
#include <hip/hip_runtime.h>

typedef unsigned short u16;
typedef unsigned int u32;
typedef __attribute__((ext_vector_type(8))) short bf16x8;
typedef __attribute__((ext_vector_type(4))) float f32x4;
typedef __attribute__((ext_vector_type(4))) u16 u16x4;

#define B_ 64
#define R_ 2
#define T_ 32
#define N_ 128
#define C_ 64

__device__ __forceinline__ u16 f2bf(float f) {
  u32 u = __builtin_bit_cast(u32, f);
  u = (u + 0x7FFFu + ((u >> 16) & 1u)) >> 16;
  return (u16)u;
}
__device__ __forceinline__ float bf2f(u16 h) {
  u32 u = ((u32)h) << 16;
  return __builtin_bit_cast(float, u);
}

#define MFMA __builtin_amdgcn_mfma_f32_16x16x32_bf16

// ---------------------------------------------------------------------------
// k_gcn helpers
// ---------------------------------------------------------------------------
__device__ __forceinline__ void a_load(float4* av, const float* Aslice, int ch, int tid) {
  const int arow = tid >> 2, aseg = tid & 3;
  const float* ap = Aslice + (size_t)(ch * 64 + arow) * N_ + aseg * 32;
#pragma unroll
  for (int j = 0; j < 8; ++j) av[j] = *(const float4*)(ap + 4 * j);
}

// consume a staged chunk: copy to outA, rowsum->dinv (folded into AT), AT write
__device__ __forceinline__ void a_consume(const float4* av, int ch, int tid,
                                          float* Oslice, u16 (*AT)[72], float* dinv) {
  const int arow = tid >> 2, aseg = tid & 3;
  const int n = ch * 64 + arow;
  float part = 0.f;
#pragma unroll
  for (int j = 0; j < 8; ++j) part += (av[j].x + av[j].y) + (av[j].z + av[j].w);
  part += __shfl_xor(part, 1);
  part += __shfl_xor(part, 2);
  const float d = rsqrtf(part + 1.0f);
  if (aseg == 0) dinv[n] = d;
  float* op = Oslice + (size_t)n * N_ + aseg * 32;
#pragma unroll
  for (int j = 0; j < 8; ++j) *(float4*)(op + 4 * j) = av[j];
  const int col = arow ^ (aseg << 4);  // swizzle: write-free, reads uniform
#pragma unroll
  for (int j = 0; j < 8; ++j) {
#pragma unroll
    for (int k = 0; k < 4; ++k) {
      const int m = aseg * 32 + 4 * j + k;
      float v = ((const float*)&av[j])[k];
      if (m == n) v += 1.0f;           // A_tilde = A + I
      AT[m][col] = f2bf(v * d);        // fold dinv[n]
    }
  }
}

__device__ __forceinline__ void load_wg(bf16x8 wf[2][2], const float* wg, int r,
                                        int wr, int lr, int lg) {
#pragma unroll
  for (int kk = 0; kk < 2; ++kk)
#pragma unroll
    for (int mr = 0; mr < 2; ++mr) {
      const float* p = wg + ((size_t)(r * C_ + 32 * wr + 16 * mr + lr)) * C_ + 32 * kk + 8 * lg;
      float4 a = *(const float4*)p, b = *(const float4*)(p + 4);
      bf16x8 f;
      f[0] = (short)f2bf(a.x); f[1] = (short)f2bf(a.y);
      f[2] = (short)f2bf(a.z); f[3] = (short)f2bf(a.w);
      f[4] = (short)f2bf(b.x); f[5] = (short)f2bf(b.y);
      f[6] = (short)f2bf(b.z); f[7] = (short)f2bf(b.w);
      wf[kk][mr] = f;
    }
}

__device__ __forceinline__ void mm2_chunk(f32x4 accr[2][4], const u16 (*TMP)[128],
                                          const u16 (*AT)[72], int ch,
                                          int wr, int wc, int lr, int lg) {
#pragma unroll
  for (int kk = 0; kk < 2; ++kk) {
    bf16x8 af[2], bfr[4];
#pragma unroll
    for (int mr = 0; mr < 2; ++mr) {
      const int c = 32 * wr + 16 * mr + lr;
      const int colT = (64 * ch + 32 * kk + 8 * lg) ^ ((lr & 3) << 4);
      af[mr] = *(const bf16x8*)&TMP[c][colT];
    }
#pragma unroll
    for (int nc = 0; nc < 4; ++nc) {
      const int m = 64 * wc + 16 * nc + lr;
      const int colA = (32 * kk + 8 * lg) ^ (((m >> 5) & 3) << 4);
      bfr[nc] = *(const bf16x8*)&AT[m][colA];
    }
#pragma unroll
    for (int mr = 0; mr < 2; ++mr)
#pragma unroll
      for (int nc = 0; nc < 4; ++nc)
        accr[mr][nc] = MFMA(af[mr], bfr[nc], accr[mr][nc], 0, 0, 0);
  }
}

// ---------------------------------------------------------------------------
// K1: per (b,t): A copy -> outA, normalized laplacian (dinv folded), gcn 1x1
// conv (MFMA), bmm with A_norm (MFMA, AT chunked), x_comb bf16 -> ws.
// LDS = 16384 + 18432 + 16384 + 512 + 512 = 52224 B -> 3 blocks/CU.
// ---------------------------------------------------------------------------
__global__ __launch_bounds__(256, 3) void k_gcn(
    const float* __restrict__ x, const float* __restrict__ A,
    const float* __restrict__ wg, const float* __restrict__ bg,
    float* __restrict__ outA, u16* __restrict__ wsX) {
  __shared__ __align__(16) u16 XT[N_][64];   // X^T [n][c^((n&3)<<4)]
  __shared__ __align__(16) u16 AT[N_][72];   // chunk: [m][n' ^ ((m>>5)<<4)]
  __shared__ __align__(16) u16 TMP[C_][128]; // tmp [c][n^((c&3)<<4)]
  __shared__ float dinv[N_];
  __shared__ float bgc[R_][C_];

  const int tid = threadIdx.x, bi = blockIdx.x;
  const int b = bi >> 5, t = bi & 31;
  const int lane = tid & 63, wv = tid >> 6;
  const int wr = wv >> 1, wc = wv & 1;
  const int lr = lane & 15, lg = lane >> 4;

  const size_t Asl0 = ((size_t)((b * R_ + 0) * T_ + t)) * (N_ * N_);
  const size_t Asl1 = ((size_t)((b * R_ + 1) * T_ + t)) * (N_ * N_);

  // ---- bulk issue: X slice, A(r0,ch0), W frags, bias
  float4 xv[8];
  {
    const int c = tid & 63, ub = tid >> 6;
    const float* xp = x + ((size_t)(b * C_ + c) * T_ + t) * N_ + 32 * ub;
#pragma unroll
    for (int j = 0; j < 8; ++j) xv[j] = *(const float4*)(xp + 4 * j);
  }
  float4 av[8];
  a_load(av, A + Asl0, 0, tid);
  if (tid < R_ * C_) ((float*)bgc)[tid] = bg[tid];
  bf16x8 wf[2][2];
  load_wg(wf, wg, 0, wr, lr, lg);

  // ---- XT write (swizzled, conflict-free)
  {
    const int c = tid & 63, ub = tid >> 6;
#pragma unroll
    for (int j = 0; j < 8; ++j) {
      const int n0 = 32 * ub + 4 * j;
      XT[n0 + 0][c ^ (0 << 4)] = f2bf(xv[j].x);
      XT[n0 + 1][c ^ (1 << 4)] = f2bf(xv[j].y);
      XT[n0 + 2][c ^ (2 << 4)] = f2bf(xv[j].z);
      XT[n0 + 3][c ^ (3 << 4)] = f2bf(xv[j].w);
    }
  }
  __syncthreads();

  f32x4 acc2[2][4] = {};

  for (int r = 0; r < R_; ++r) {
    const size_t Asl = r ? Asl1 : Asl0;
    // ---- mm1: TMP[o][n] = W_r[o][:] . X[:][n] + bias
    {
      f32x4 acc1[2][4] = {};
#pragma unroll
      for (int kk = 0; kk < 2; ++kk) {
        bf16x8 bfr[4];
#pragma unroll
        for (int nc = 0; nc < 4; ++nc) {
          const int n = 64 * wc + 16 * nc + lr;
          const int col = (32 * kk + 8 * lg) ^ ((lr & 3) << 4);
          bfr[nc] = *(const bf16x8*)&XT[n][col];
        }
#pragma unroll
        for (int mr = 0; mr < 2; ++mr)
#pragma unroll
          for (int nc = 0; nc < 4; ++nc)
            acc1[mr][nc] = MFMA(wf[kk][mr], bfr[nc], acc1[mr][nc], 0, 0, 0);
      }
#pragma unroll
      for (int mr = 0; mr < 2; ++mr) {
        const int o0 = 32 * wr + 16 * mr + 4 * lg;
#pragma unroll
        for (int nc = 0; nc < 4; ++nc) {
          const int n = 64 * wc + 16 * nc + lr;
#pragma unroll
          for (int i = 0; i < 4; ++i)
            TMP[o0 + i][n ^ (i << 4)] = f2bf(acc1[mr][nc][i] + bgc[r][o0 + i]);
        }
      }
    }
    // ---- consume chunk0 (AT, dinv-lo, A copy); issue chunk1 loads
    a_consume(av, 0, tid, outA + Asl, AT, dinv);
    float4 av2[8];
    a_load(av2, A + Asl, 1, tid);
    __syncthreads();  // B1: TMP + AT0 + dinv-lo ready

    f32x4 accr[2][4] = {};
    mm2_chunk(accr, TMP, AT, 0, wr, wc, lr, lg);
    __syncthreads();  // B2: AT0 consumed

    a_consume(av2, 1, tid, outA + Asl, AT, dinv);
    if (r == 0) {
      a_load(av, A + Asl1, 0, tid);     // prefetch next relation
      load_wg(wf, wg, 1, wr, lr, lg);
    }
    __syncthreads();  // B3: AT1 + dinv-hi ready

    mm2_chunk(accr, TMP, AT, 1, wr, wc, lr, lg);
    // fold dinv[m] per relation, accumulate into acc2
#pragma unroll
    for (int nc = 0; nc < 4; ++nc) {
      const float dm = dinv[64 * wc + 16 * nc + lr];
#pragma unroll
      for (int mr = 0; mr < 2; ++mr)
#pragma unroll
        for (int i = 0; i < 4; ++i)
          acc2[mr][nc][i] += dm * accr[mr][nc][i];
    }
    if (r == 0) __syncthreads();  // B4: TMP/AT/dinv reusable
  }

  // ---- epilogue: ws[b][t][m][c] = bf16(x_comb)
  {
    u16* wp = wsX + ((size_t)(b * T_ + t) * N_) * C_;
#pragma unroll
    for (int mr = 0; mr < 2; ++mr)
#pragma unroll
      for (int nc = 0; nc < 4; ++nc) {
        const int m = 64 * wc + 16 * nc + lr;
        const int cb = 32 * wr + 16 * mr + 4 * lg;
        u16x4 pk;
#pragma unroll
        for (int i = 0; i < 4; ++i) pk[i] = f2bf(acc2[mr][nc][i]);
        *(u16x4*)(wp + (size_t)m * C_ + cb) = pk;
      }
  }
}

// ---------------------------------------------------------------------------
// K2: per (b,t): h = prelu(x_comb); out = prelu(conv3_T(h) + b_tcn + x)
// W in register fragments (stride-3 gathers, L2-hot). LDS = 51200 -> 3/CU.
// ---------------------------------------------------------------------------
__global__ __launch_bounds__(256, 3) void k_tcn(
    const u16* __restrict__ wsX, const float* __restrict__ x,
    const float* __restrict__ wt, const float* __restrict__ bt,
    const float* __restrict__ a_tcn, const float* __restrict__ a_out,
    float* __restrict__ out) {
  __shared__ __align__(16) u16 HT[N_][200];  // H^T [n][k=dt*64+ci], 200 pad: b128-aligned
  const int tid = threadIdx.x, bi = blockIdx.x;
  const int b = bi >> 5, t = bi & 31;
  const int lane = tid & 63, wv = tid >> 6;
  const int wr = wv >> 1, wc = wv & 1;
  const int lr = lane & 15, lg = lane >> 4;
  const float at = a_tcn[0], ao = a_out[0];

  // W fragments: k = dt*64+ci -> wt[((co*64+ci)*3 + dt], stride-3 gathers
  bf16x8 wfr[6][2];
#pragma unroll
  for (int kk = 0; kk < 6; ++kk) {
    const int dt = kk >> 1;
    const int ci0 = (32 * kk + 8 * lg) & 63;
#pragma unroll
    for (int mr = 0; mr < 2; ++mr) {
      const int co = 32 * wr + 16 * mr + lr;
      const float* p = wt + ((size_t)co * C_ + ci0) * 3 + dt;
      float e[8];
#pragma unroll
      for (int j = 0; j < 8; ++j) e[j] = p[3 * j];
      bf16x8 f;
#pragma unroll
      for (int j = 0; j < 8; ++j) f[j] = (short)f2bf(e[j]);
      wfr[kk][mr] = f;
    }
  }

#pragma unroll
  for (int dt = 0; dt < 3; ++dt) {
    const int t2 = t + dt - 1;
    const bool ok = (t2 >= 0) && (t2 < T_);
    const u16* p = wsX + ((size_t)(b * T_ + (ok ? t2 : 0)) * N_) * C_;
    u16x4 hv[8];
#pragma unroll
    for (int it = 0; it < 8; ++it) {
      const int idx = it * 256 + tid;
      const int n = idx >> 4, c4 = (idx & 15) * 4;
      u16x4 z = {0, 0, 0, 0};
      hv[it] = ok ? *(const u16x4*)(p + n * C_ + c4) : z;
    }
#pragma unroll
    for (int it = 0; it < 8; ++it) {
      const int idx = it * 256 + tid;
      const int n = idx >> 4, c4 = (idx & 15) * 4;
      u16x4 o;
#pragma unroll
      for (int j = 0; j < 4; ++j) {
        float f = bf2f(hv[it][j]);
        o[j] = f2bf(f < 0.f ? at * f : f);
      }
      *(u16x4*)&HT[n][dt * 64 + c4] = o;
    }
  }
  __syncthreads();

  f32x4 acc[2][4] = {};
#pragma unroll
  for (int kk = 0; kk < 6; ++kk) {
    bf16x8 bfr[4];
#pragma unroll
    for (int nc = 0; nc < 4; ++nc)
      bfr[nc] = *(const bf16x8*)&HT[64 * wc + 16 * nc + lr][32 * kk + 8 * lg];
#pragma unroll
    for (int mr = 0; mr < 2; ++mr)
#pragma unroll
      for (int nc = 0; nc < 4; ++nc)
        acc[mr][nc] = MFMA(wfr[kk][mr], bfr[nc], acc[mr][nc], 0, 0, 0);
  }

#pragma unroll
  for (int mr = 0; mr < 2; ++mr) {
    const int co0 = 32 * wr + 16 * mr + 4 * lg;
    float bts[4];
#pragma unroll
    for (int i = 0; i < 4; ++i) bts[i] = bt[co0 + i];
#pragma unroll
    for (int nc = 0; nc < 4; ++nc) {
      const int n = 64 * wc + 16 * nc + lr;
#pragma unroll
      for (int i = 0; i < 4; ++i) {
        const size_t gi = ((size_t)(b * C_ + co0 + i) * T_ + t) * N_ + n;
        float v = acc[mr][nc][i] + bts[i] + x[gi];
        out[gi] = (v < 0.f) ? ao * v : v;
      }
    }
  }
}

extern "C" void kernel_launch(void* const* d_in, const int* in_sizes, int n_in,
                              void* d_out, int out_size, void* d_ws, size_t ws_size,
                              hipStream_t stream) {
  const float* x = (const float*)d_in[0];
  const float* A = (const float*)d_in[1];
  const float* wg = (const float*)d_in[2];
  const float* bg = (const float*)d_in[3];
  const float* wt = (const float*)d_in[4];
  const float* bt = (const float*)d_in[5];
  const float* atc = (const float*)d_in[6];
  const float* aoc = (const float*)d_in[7];
  float* out = (float*)d_out;
  float* outA = out + (size_t)B_ * C_ * T_ * N_;  // second tuple element: A copy
  u16* wsX = (u16*)d_ws;                          // bf16 x_comb, (B,T,N,C) = 33.5 MB

  k_gcn<<<B_ * T_, 256, 0, stream>>>(x, A, wg, bg, outA, wsX);
  k_tcn<<<B_ * T_, 256, 0, stream>>>(wsX, x, wt, bt, atc, aoc, out);
}